// Round 3
// baseline (774.462 us; speedup 1.0000x reference)
//
#include <hip/hip_runtime.h>
#include <hip/hip_cooperative_groups.h>
#include <stdint.h>

namespace cg = cooperative_groups;

// GAT forward, MI355X. FP32 in/out; edge_index int32. N=50000, E=800000,
// HEADS=4, C=64 (HC=256).
// Pipeline (R11):
//   csr (cooperative, 1 dispatch): P0 zero-deg + trans(W->frag-major split
//        bf16) | P1 hist | P2 block scans | P3 spine | P4 prefix+cur |
//        P5 scatter. Replaces 6 dispatches (memset,trans,hist,scanA,scanC,
//        scatter) — non-gather time was ~222us vs ~60us of real work, i.e.
//        ~8us/dispatch of gap (measured R8->R9 delta).
//   gemm: H = x@W via split-bf16 MFMA (3 terms, err ~2^-17), H stored bf16.
//        att logits a_src/a_dst fused in epilogue (wave=head).
//   gather: out = (w_self*h_i + sum_j w_j*h_j)/(sum w) + bias, PReLU.
//        R11: one wave per (node, head-pair); 2 ch/lane; 32-edge phase A
//        (1 cp load + 1 a_src load + 1 exp per lane per 32 edges); 16-row
//        sub-batches (hv = 16 dwords -> VGPR ~40, occupancy up from R10's
//        34%). Head-pair steered to XCD half via blockIdx&7 (blocks
//        round-robin XCDs): XCDs 0-3 touch only bytes [0,256) of H rows,
//        XCDs 4-7 only [256,512) -> per-XCD H footprint halves -> L2 hit
//        up, FETCH (was 211MB = 8x H) down.
// Softmax shift omitted: logits fp32-exact-ish (err ~1e-4), |e|<~12 ->
// exp<=1.6e5, fp32-safe; softmax is shift-invariant. Dominant output error =
// bf16 H storage (~0.016 absmax vs 0.0575 threshold, verified rounds 3-10).

using u16 = unsigned short;
typedef float f32x4 __attribute__((ext_vector_type(4)));
typedef __bf16 bf16x8 __attribute__((ext_vector_type(8)));
typedef u16 u16x8 __attribute__((ext_vector_type(8)));

#define NEG 0.2f
#define APAD 264   // 256 + 8 u16 pad: row stride 528 B -> 2-way LDS aliasing (free)

__device__ __forceinline__ float bf2f(u16 u) {
    union { uint32_t i; float f; } v; v.i = ((uint32_t)u) << 16; return v.f;
}
__device__ __forceinline__ u16 f2bf(float f) {          // RNE
    union { float f; uint32_t i; } v; v.f = f;
    uint32_t r = v.i + 0x7FFFu + ((v.i >> 16) & 1u);
    return (u16)(r >> 16);
}
// trunc split: f ~= hi + lo with |err| ~ 2^-17 |f|
__device__ __forceinline__ void split2(float f, u16& h, u16& l) {
    union { float f; uint32_t i; } v; v.f = f;
    h = (u16)(v.i >> 16);
    float r = f - bf2f(h);
    union { float f; uint32_t i; } w; w.f = r;
    l = (u16)(w.i >> 16);
}
__device__ __forceinline__ float wexp(float e) {
    e = e >= 0.f ? e : NEG * e;
    return __expf(e);
}

// ---------------- cooperative CSR build (+trans) ---------------------------
__global__ __launch_bounds__(256) void csr_kernel(
    const float* __restrict__ W, u16* __restrict__ Wfh, u16* __restrict__ Wfl,
    const int* __restrict__ esrc, const int* __restrict__ edst,
    int* __restrict__ deg, int* __restrict__ offs, int* __restrict__ cur,
    int* __restrict__ bsum, int* __restrict__ csr_src, int E, int Nn)
{
    cg::grid_group grid = cg::this_grid();
    const int tid = threadIdx.x;
    const int gt = blockIdx.x * 256 + tid;
    const int gs = gridDim.x * 256;
    __shared__ int wsum[4];

    // ---- P0: zero deg; blocks 0..31 also transpose/split W ----
    for (int i = gt; i < Nn; i += gs) deg[i] = 0;
    if (blockIdx.x < 32) {
        // Wf[((kg*16+nb)*64+l)*8+j] =
        //   split(W[(kg*32+(l>>4)*8+j)*256 + nb*16+(l&15)])
        const int f = blockIdx.x * 4 + (tid >> 6);
        const int l = tid & 63;
        const int kg = f >> 4, nb = f & 15;
        const int n = nb * 16 + (l & 15);
        const int kb = kg * 32 + (l >> 4) * 8;
        u16x8 hv, lv;
#pragma unroll
        for (int j = 0; j < 8; j++) {
            u16 th, tl;
            split2(W[(size_t)(kb + j) * 256 + n], th, tl);
            hv[j] = th;
            lv[j] = tl;
        }
        *(u16x8*)(Wfh + ((size_t)f * 64 + l) * 8) = hv;
        *(u16x8*)(Wfl + ((size_t)f * 64 + l) * 8) = lv;
    }
    grid.sync();

    // ---- P1: histogram of destinations ----
    for (int e = gt; e < E; e += gs) {
        int i = edst[e];
        i = ((unsigned)i < (unsigned)Nn) ? i : 0;
        atomicAdd(&deg[i], 1);
    }
    grid.sync();

    // ---- P2: per-block (256-elem) exclusive scan of deg ----
    const int nblk = (Nn + 255) >> 8;
    if (blockIdx.x < nblk) {
        const int idx = (blockIdx.x << 8) + tid;
        const int ln = tid & 63, wv = tid >> 6;
        int v = (idx < Nn) ? deg[idx] : 0;
        int s = v;
#pragma unroll
        for (int o = 1; o < 64; o <<= 1) {
            int u = __shfl_up(s, o, 64);
            if (ln >= o) s += u;
        }
        if (ln == 63) wsum[wv] = s;
        __syncthreads();
        int wpre = 0;
#pragma unroll
        for (int w2 = 0; w2 < 4; w2++) wpre += (w2 < wv) ? wsum[w2] : 0;
        if (idx < Nn) offs[idx] = wpre + s - v;      // block-local exclusive
        if (tid == 255) bsum[blockIdx.x] = wpre + s; // block total
    }
    grid.sync();

    // ---- P3: spine exclusive scan of bsum[0..nblk) (block 0; nblk<=256) ---
    if (blockIdx.x == 0) {
        const int ln = tid & 63, wv = tid >> 6;
        int v = (tid < nblk) ? bsum[tid] : 0;
        int s = v;
#pragma unroll
        for (int o = 1; o < 64; o <<= 1) {
            int u = __shfl_up(s, o, 64);
            if (ln >= o) s += u;
        }
        __syncthreads();                 // wsum reuse from P2
        if (ln == 63) wsum[wv] = s;
        __syncthreads();
        int wpre = 0;
#pragma unroll
        for (int w2 = 0; w2 < 4; w2++) wpre += (w2 < wv) ? wsum[w2] : 0;
        if (tid < nblk) bsum[tid] = wpre + s - v;    // exclusive
    }
    grid.sync();

    // ---- P4: add spine prefix; init cur ----
    if (blockIdx.x < nblk) {
        const int idx = (blockIdx.x << 8) + tid;
        if (idx < Nn) {
            int o = offs[idx] + bsum[blockIdx.x];
            offs[idx] = o;
            cur[idx] = o;
        }
    }
    grid.sync();

    // ---- P5: scatter edges into CSR ----
    for (int e = gt; e < E; e += gs) {
        int j = esrc[e], i = edst[e];
        j = ((unsigned)j < (unsigned)Nn) ? j : 0;
        i = ((unsigned)i < (unsigned)Nn) ? i : 0;
        int pos = atomicAdd(&cur[i], 1);
        if ((unsigned)pos < (unsigned)E) csr_src[pos] = j;
    }
}

// ---------------- GEMM: H = x @ W, LDS-staged A, frag-major B --------------
// att logits fused into the epilogue (wave w owns head w's columns).
__global__ __launch_bounds__(256, 2) void gemm_kernel(
    const float* __restrict__ X, const u16* __restrict__ Wfh,
    const u16* __restrict__ Wfl, const float* __restrict__ attS,
    const float* __restrict__ attD, u16* __restrict__ H,
    float* __restrict__ a_src, float* __restrict__ a_dst, int Nn)
{
    __shared__ u16 Ah[64 * APAD];
    __shared__ u16 Al[64 * APAD];
    const int tid = threadIdx.x, m0 = blockIdx.x * 64;
    const int wave = tid >> 6, lane = tid & 63;
    const int quad = lane >> 4, lr = lane & 15;

    // ---- stage X tile (64 rows x 256 cols) as split bf16 ----
#pragma unroll
    for (int i = 0; i < 16; i++) {
        const int f = i * 256 + tid;            // float4 index in tile
        const int row = f >> 6;                 // 64 float4 per row
        const int c4 = (f & 63) * 4;
        int grow = m0 + row;
        if (grow >= Nn) grow = Nn - 1;          // clamp; stores guarded
        const float4 v = *(const float4*)(X + (size_t)grow * 256 + c4);
        u16 h0, l0, h1, l1, h2, l2, h3, l3;
        split2(v.x, h0, l0); split2(v.y, h1, l1);
        split2(v.z, h2, l2); split2(v.w, h3, l3);
        uint2 hp, lp;
        hp.x = (uint32_t)h0 | ((uint32_t)h1 << 16);
        hp.y = (uint32_t)h2 | ((uint32_t)h3 << 16);
        lp.x = (uint32_t)l0 | ((uint32_t)l1 << 16);
        lp.y = (uint32_t)l2 | ((uint32_t)l3 << 16);
        *(uint2*)(Ah + row * APAD + c4) = hp;   // 8B aligned
        *(uint2*)(Al + row * APAD + c4) = lp;
    }
    __syncthreads();

    f32x4 acc[4][4] = {};                       // [mi][ni]
    bf16x8 bh[2][4], bl[2][4];                  // B double buffer

    // prologue: kg=0 B frags (frag id = kg*16 + wave*4 + ni)
#pragma unroll
    for (int ni = 0; ni < 4; ni++) {
        const size_t o = ((size_t)(wave * 4 + ni) * 64 + lane) * 8;
        bh[0][ni] = *(const bf16x8*)(Wfh + o);
        bl[0][ni] = *(const bf16x8*)(Wfl + o);
    }

#pragma unroll
    for (int kg = 0; kg < 8; kg++) {
        const int st = kg & 1, ns = st ^ 1;
        if (kg < 7) {                           // prefetch kg+1 B
#pragma unroll
            for (int ni = 0; ni < 4; ni++) {
                const size_t o = ((size_t)((kg + 1) * 16 + wave * 4 + ni) * 64 + lane) * 8;
                bh[ns][ni] = *(const bf16x8*)(Wfh + o);
                bl[ns][ni] = *(const bf16x8*)(Wfl + o);
            }
        }
        bf16x8 ah[4], al[4];
#pragma unroll
        for (int mi = 0; mi < 4; mi++) {
            const int o = (mi * 16 + lr) * APAD + kg * 32 + quad * 8;
            ah[mi] = *(const bf16x8*)(Ah + o);  // ds_read_b128
            al[mi] = *(const bf16x8*)(Al + o);
        }
#pragma unroll
        for (int ni = 0; ni < 4; ni++)
#pragma unroll
            for (int mi = 0; mi < 4; mi++) {
                acc[mi][ni] = __builtin_amdgcn_mfma_f32_16x16x32_bf16(
                    ah[mi], bh[st][ni], acc[mi][ni], 0, 0, 0);
                acc[mi][ni] = __builtin_amdgcn_mfma_f32_16x16x32_bf16(
                    ah[mi], bl[st][ni], acc[mi][ni], 0, 0, 0);
                acc[mi][ni] = __builtin_amdgcn_mfma_f32_16x16x32_bf16(
                    al[mi], bh[st][ni], acc[mi][ni], 0, 0, 0);
            }
    }

    // ---- epilogue 1: att logits from fp32 acc (wave = head) ----
    // a_src[row][wave] = sum_c acc(row, c) * attS[wave][c]; c = ni*16+lr.
    {
        float asv[4], adv[4];
#pragma unroll
        for (int ni = 0; ni < 4; ni++) {
            asv[ni] = attS[wave * 64 + ni * 16 + lr];
            adv[ni] = attD[wave * 64 + ni * 16 + lr];
        }
#pragma unroll
        for (int mi = 0; mi < 4; mi++)
#pragma unroll
            for (int r = 0; r < 4; r++) {
                float ps = 0.f, pd = 0.f;
#pragma unroll
                for (int ni = 0; ni < 4; ni++) {
                    ps += acc[mi][ni][r] * asv[ni];
                    pd += acc[mi][ni][r] * adv[ni];
                }
#pragma unroll
                for (int off = 8; off >= 1; off >>= 1) {
                    ps += __shfl_xor(ps, off, 16);   // reduce over lr group
                    pd += __shfl_xor(pd, off, 16);
                }
                if (lr == 0) {
                    const int row = m0 + mi * 16 + quad * 4 + r;
                    if (row < Nn) {
                        a_src[row * 4 + wave] = ps;
                        a_dst[row * 4 + wave] = pd;
                    }
                }
            }
    }

    // ---- epilogue 2: H store. C/D: col = lane&15 (lr), row = quad*4 + r ---
    const int n0 = wave * 64;
#pragma unroll
    for (int mi = 0; mi < 4; mi++)
#pragma unroll
        for (int ni = 0; ni < 4; ni++) {
            int col = n0 + ni * 16 + lr;
#pragma unroll
            for (int r = 0; r < 4; r++) {
                int row = m0 + mi * 16 + quad * 4 + r;
                if (row < Nn) H[(size_t)row * 256 + col] = f2bf(acc[mi][ni][r]);
            }
        }
}

// ---------------- gather: 1 wave/(node, head-pair), 2 ch/thread ------------
// blockIdx = g*8 + s; s&3 picks node sub-group, s>>2 picks head-pair ->
// blocks round-robin XCDs, so XCDs 0-3 serve hp=0 (bytes [0,256) of each H
// row) and XCDs 4-7 serve hp=1. 32-edge phase A: lane sub=lane&31 loads edge
// id + a_src + exp ONCE per 32 edges of its head; ids/weights broadcast via
// __shfl width 32. Rows processed in 16-deep sub-batches (skipped if the
// whole sub-batch is past the tail); dead slots clamp to the last valid
// edge's row (cache-hot, w=0).
__global__ __launch_bounds__(256) void gather_kernel(
    const u16* __restrict__ H, const int* __restrict__ offs,
    const int* __restrict__ deg, const int* __restrict__ csr_src,
    const float* __restrict__ a_src, const float* __restrict__ a_dst,
    const float* __restrict__ bias, const float* __restrict__ prelu,
    float* __restrict__ out, int Nn)
{
    const int wave = threadIdx.x >> 6, lane = threadIdx.x & 63;
    const int g = blockIdx.x >> 3, s = blockIdx.x & 7;
    const int hp = s >> 2;                        // head-pair -> XCD half
    const int node = ((g << 2) + (s & 3)) * 4 + wave;
    if (node >= Nn) return;
    const int hh = lane >> 5;
    const int head = (hp << 1) + hh;
    const int sub = lane & 31;
    const int ch = (head << 6) + sub * 2;         // 2 channels / lane

    const float adv = a_dst[node * 4 + head];
    const float ws = wexp(a_src[node * 4 + head] + adv);
    float acc0, acc1, sumw = 0.f;                 // sumw: own edges only
    {   // self loop
        const uint32_t hv = *(const uint32_t*)(H + (size_t)node * 256 + ch);
        acc0 = ws * bf2f((u16)hv);
        acc1 = ws * bf2f((u16)(hv >> 16));
    }
    const int d = deg[node];
    const int* __restrict__ cp = csr_src + offs[node];

    for (int k = 0; k < d; k += 32) {
        const int q = d - k;                      // edges left (>=1)
        const int es = (sub < q) ? sub : q - 1;
        const int jj = cp[k + es];                // in-range always
        float ww = wexp(a_src[jj * 4 + head] + adv);
        ww = (sub < q) ? ww : 0.f;
        sumw += ww;
        const int nh = (q > 16) ? 2 : 1;
        for (int half = 0; half < nh; half++) {
            const int hb = half << 4;
            uint32_t hv[16];
#pragma unroll
            for (int t = 0; t < 16; t++) {
                const int jt = __shfl(jj, hb + t, 32);
                hv[t] = *(const uint32_t*)(H + ((size_t)jt << 8) + ch);
            }
#pragma unroll
            for (int t = 0; t < 16; t++) {
                const float w = __shfl(ww, hb + t, 32);
                acc0 += w * bf2f((u16)hv[t]);
                acc1 += w * bf2f((u16)(hv[t] >> 16));
            }
        }
    }
    // total edge weight: reduce per-lane partials over the 32-lane head group
#pragma unroll
    for (int off = 16; off >= 1; off >>= 1)
        sumw += __shfl_xor(sumw, off, 32);

    const float inv = 1.f / (ws + sumw + 1e-16f);
    const float pa = prelu[0];
    float o0 = acc0 * inv + bias[ch];
    float o1 = acc1 * inv + bias[ch + 1];
    o0 = o0 >= 0.f ? o0 : pa * o0;
    o1 = o1 >= 0.f ? o1 : pa * o1;
    float2 ov; ov.x = o0; ov.y = o1;
    *(float2*)(out + (size_t)node * 256 + ch) = ov;
}

// ---------------------------------------------------------------------------
extern "C" void kernel_launch(void* const* d_in, const int* in_sizes, int n_in,
                              void* d_out, int out_size, void* d_ws, size_t ws_size,
                              hipStream_t stream)
{
    const float* X    = (const float*)d_in[0];
    const int*   EI   = (const int*)d_in[1];
    const float* W    = (const float*)d_in[2];
    const float* attS = (const float*)d_in[3];
    const float* attD = (const float*)d_in[4];
    const float* bias = (const float*)d_in[5];
    const float* pa   = (const float*)d_in[6];

    const int Nn = in_sizes[0] / 256;   // 50000
    const int E  = in_sizes[1] / 2;     // 800000
    const int* esrc = EI;
    const int* edst = EI + E;

    // workspace carve (~31 MB), all segments 16B-aligned
    char* p = (char*)d_ws;
    u16*   H       = (u16*)p;   p += (size_t)Nn * 256 * 2;
    float* a_src   = (float*)p; p += (size_t)Nn * 4 * 4;
    float* a_dst   = (float*)p; p += (size_t)Nn * 4 * 4;
    u16*   Wfh     = (u16*)p;   p += 256 * 256 * 2;
    u16*   Wfl     = (u16*)p;   p += 256 * 256 * 2;
    int*   deg     = (int*)p;   p += (size_t)Nn * 4;
    int*   offs    = (int*)p;   p += (size_t)Nn * 4;
    int*   cur     = (int*)p;   p += (size_t)Nn * 4;
    int*   bsum    = (int*)p;   p += 256 * 4;
    int*   csr_src = (int*)p;   p += ((size_t)E + 16) * 4;

    // ---- 1: cooperative CSR build (+trans). 1024 blocks = 4/CU, trivially
    //         co-resident (LDS 16B, low VGPR). ----
    int Ei = E, Ni = Nn;
    void* cargs[] = { (void*)&W, (void*)&Wfh, (void*)&Wfl,
                      (void*)&esrc, (void*)&edst,
                      (void*)&deg, (void*)&offs, (void*)&cur,
                      (void*)&bsum, (void*)&csr_src,
                      (void*)&Ei, (void*)&Ni };
    (void)hipLaunchCooperativeKernel((const void*)csr_kernel,
                                     dim3(1024), dim3(256), cargs, 0, stream);

    // ---- 2: GEMM + fused att logits ----
    gemm_kernel<<<(Nn + 63) / 64, 256, 0, stream>>>(X, Wfh, Wfl, attS, attD,
                                                    H, a_src, a_dst, Nn);

    // ---- 3: gather. grid = ceil(Nn/16) node-groups x 8 (4 node-subgroups
    //         x 2 head-pairs), steering head-pair -> XCD half. ----
    const int gblocks = ((Nn + 15) / 16) * 8;
    gather_kernel<<<gblocks, 256, 0, stream>>>(H, offs, deg, csr_src,
                                               a_src, a_dst, bias, pa,
                                               (float*)d_out, Nn);
}

// Round 4
// 299.039 us; speedup vs baseline: 2.5898x; 2.5898x over previous
//
#include <hip/hip_runtime.h>
#include <stdint.h>

// GAT forward, MI355X. FP32 in/out; edge_index int32. N=50000, E=800000,
// HEADS=4, C=64 (HC=256).
// Pipeline (R12):
//   prep:  trans (W -> frag-major split bf16, blocks 0..31) + zero deg +
//          zero scan flags, one kernel (memset dispatch folded in).
//   gemm:  H = x@W via split-bf16 MFMA (3 terms, err ~2^-17), H stored bf16.
//          att logits a_src/a_dst fused in epilogue (wave=head).
//   hist:  degree histogram (atomics).
//   scan:  ONE decoupled-lookback exclusive scan (merges R10's scanA+scanC;
//          49 blocks x 1024 thr, all co-resident; lane 0 polls predecessor
//          flags via device-scope atomics — NO cg grid.sync, which R11
//          measured at ~110us/sync).
//   scatter: CSR fill.
//   gather: out = (w_self*h_i + sum_j w_j*h_j)/(sum w) + bias, PReLU.
//          One wave per (node, head-pair); 2 ch/lane; 32-edge phase A (1 cp
//          load + 1 a_src load + 1 exp per lane per 32 edges of its head);
//          ids/weights broadcast via __shfl width 32; 16-deep row sub-
//          batches (VGPR ~40). Head-pair steered to XCD half via blockIdx&7
//          (blocks round-robin XCDs): XCDs 0-3 touch only bytes [0,256) of
//          each H row, XCDs 4-7 only [256,512) -> per-XCD footprint halves.
// Softmax shift omitted: logits fp32-exact-ish (err ~1e-4), |e|<~12 ->
// exp<=1.6e5, fp32-safe; softmax is shift-invariant. Dominant output error =
// bf16 H storage (~0.016 absmax vs 0.0575 threshold, verified rounds 3-11).

using u16 = unsigned short;
typedef float f32x4 __attribute__((ext_vector_type(4)));
typedef __bf16 bf16x8 __attribute__((ext_vector_type(8)));
typedef u16 u16x8 __attribute__((ext_vector_type(8)));

#define NEG 0.2f
#define APAD 264   // 256 + 8 u16 pad: row stride 528 B -> 2-way LDS aliasing (free)

__device__ __forceinline__ float bf2f(u16 u) {
    union { uint32_t i; float f; } v; v.i = ((uint32_t)u) << 16; return v.f;
}
__device__ __forceinline__ u16 f2bf(float f) {          // RNE
    union { float f; uint32_t i; } v; v.f = f;
    uint32_t r = v.i + 0x7FFFu + ((v.i >> 16) & 1u);
    return (u16)(r >> 16);
}
// trunc split: f ~= hi + lo with |err| ~ 2^-17 |f|
__device__ __forceinline__ void split2(float f, u16& h, u16& l) {
    union { float f; uint32_t i; } v; v.f = f;
    h = (u16)(v.i >> 16);
    float r = f - bf2f(h);
    union { float f; uint32_t i; } w; w.f = r;
    l = (u16)(w.i >> 16);
}
__device__ __forceinline__ float wexp(float e) {
    e = e >= 0.f ? e : NEG * e;
    return __expf(e);
}

// ---------------- prep: trans (blocks 0..31) + zero deg/flags --------------
__global__ __launch_bounds__(256) void prep_kernel(
    const float* __restrict__ W, u16* __restrict__ Wfh, u16* __restrict__ Wfl,
    int* __restrict__ deg, unsigned* __restrict__ bflag, int Nn, int nscan)
{
    const int tid = threadIdx.x;
    const int gt = blockIdx.x * 256 + tid;
    const int gs = gridDim.x * 256;
    for (int i = gt; i < Nn; i += gs) deg[i] = 0;
    if (gt < nscan) bflag[gt] = 0u;
    if (blockIdx.x < 32) {
        // Wf[((kg*16+nb)*64+l)*8+j] =
        //   split(W[(kg*32+(l>>4)*8+j)*256 + nb*16+(l&15)])
        const int f = blockIdx.x * 4 + (tid >> 6);
        const int l = tid & 63;
        const int kg = f >> 4, nb = f & 15;
        const int n = nb * 16 + (l & 15);
        const int kb = kg * 32 + (l >> 4) * 8;
        u16x8 hv, lv;
#pragma unroll
        for (int j = 0; j < 8; j++) {
            u16 th, tl;
            split2(W[(size_t)(kb + j) * 256 + n], th, tl);
            hv[j] = th;
            lv[j] = tl;
        }
        *(u16x8*)(Wfh + ((size_t)f * 64 + l) * 8) = hv;
        *(u16x8*)(Wfl + ((size_t)f * 64 + l) * 8) = lv;
    }
}

// ---------------- GEMM: H = x @ W, LDS-staged A, frag-major B --------------
// att logits fused into the epilogue (wave w owns head w's columns).
__global__ __launch_bounds__(256, 2) void gemm_kernel(
    const float* __restrict__ X, const u16* __restrict__ Wfh,
    const u16* __restrict__ Wfl, const float* __restrict__ attS,
    const float* __restrict__ attD, u16* __restrict__ H,
    float* __restrict__ a_src, float* __restrict__ a_dst, int Nn)
{
    __shared__ u16 Ah[64 * APAD];
    __shared__ u16 Al[64 * APAD];
    const int tid = threadIdx.x, m0 = blockIdx.x * 64;
    const int wave = tid >> 6, lane = tid & 63;
    const int quad = lane >> 4, lr = lane & 15;

    // ---- stage X tile (64 rows x 256 cols) as split bf16 ----
#pragma unroll
    for (int i = 0; i < 16; i++) {
        const int f = i * 256 + tid;            // float4 index in tile
        const int row = f >> 6;                 // 64 float4 per row
        const int c4 = (f & 63) * 4;
        int grow = m0 + row;
        if (grow >= Nn) grow = Nn - 1;          // clamp; stores guarded
        const float4 v = *(const float4*)(X + (size_t)grow * 256 + c4);
        u16 h0, l0, h1, l1, h2, l2, h3, l3;
        split2(v.x, h0, l0); split2(v.y, h1, l1);
        split2(v.z, h2, l2); split2(v.w, h3, l3);
        uint2 hp, lp;
        hp.x = (uint32_t)h0 | ((uint32_t)h1 << 16);
        hp.y = (uint32_t)h2 | ((uint32_t)h3 << 16);
        lp.x = (uint32_t)l0 | ((uint32_t)l1 << 16);
        lp.y = (uint32_t)l2 | ((uint32_t)l3 << 16);
        *(uint2*)(Ah + row * APAD + c4) = hp;   // 8B aligned
        *(uint2*)(Al + row * APAD + c4) = lp;
    }
    __syncthreads();

    f32x4 acc[4][4] = {};                       // [mi][ni]
    bf16x8 bh[2][4], bl[2][4];                  // B double buffer

    // prologue: kg=0 B frags (frag id = kg*16 + wave*4 + ni)
#pragma unroll
    for (int ni = 0; ni < 4; ni++) {
        const size_t o = ((size_t)(wave * 4 + ni) * 64 + lane) * 8;
        bh[0][ni] = *(const bf16x8*)(Wfh + o);
        bl[0][ni] = *(const bf16x8*)(Wfl + o);
    }

#pragma unroll
    for (int kg = 0; kg < 8; kg++) {
        const int st = kg & 1, ns = st ^ 1;
        if (kg < 7) {                           // prefetch kg+1 B
#pragma unroll
            for (int ni = 0; ni < 4; ni++) {
                const size_t o = ((size_t)((kg + 1) * 16 + wave * 4 + ni) * 64 + lane) * 8;
                bh[ns][ni] = *(const bf16x8*)(Wfh + o);
                bl[ns][ni] = *(const bf16x8*)(Wfl + o);
            }
        }
        bf16x8 ah[4], al[4];
#pragma unroll
        for (int mi = 0; mi < 4; mi++) {
            const int o = (mi * 16 + lr) * APAD + kg * 32 + quad * 8;
            ah[mi] = *(const bf16x8*)(Ah + o);  // ds_read_b128
            al[mi] = *(const bf16x8*)(Al + o);
        }
#pragma unroll
        for (int ni = 0; ni < 4; ni++)
#pragma unroll
            for (int mi = 0; mi < 4; mi++) {
                acc[mi][ni] = __builtin_amdgcn_mfma_f32_16x16x32_bf16(
                    ah[mi], bh[st][ni], acc[mi][ni], 0, 0, 0);
                acc[mi][ni] = __builtin_amdgcn_mfma_f32_16x16x32_bf16(
                    ah[mi], bl[st][ni], acc[mi][ni], 0, 0, 0);
                acc[mi][ni] = __builtin_amdgcn_mfma_f32_16x16x32_bf16(
                    al[mi], bh[st][ni], acc[mi][ni], 0, 0, 0);
            }
    }

    // ---- epilogue 1: att logits from fp32 acc (wave = head) ----
    // a_src[row][wave] = sum_c acc(row, c) * attS[wave][c]; c = ni*16+lr.
    {
        float asv[4], adv[4];
#pragma unroll
        for (int ni = 0; ni < 4; ni++) {
            asv[ni] = attS[wave * 64 + ni * 16 + lr];
            adv[ni] = attD[wave * 64 + ni * 16 + lr];
        }
#pragma unroll
        for (int mi = 0; mi < 4; mi++)
#pragma unroll
            for (int r = 0; r < 4; r++) {
                float ps = 0.f, pd = 0.f;
#pragma unroll
                for (int ni = 0; ni < 4; ni++) {
                    ps += acc[mi][ni][r] * asv[ni];
                    pd += acc[mi][ni][r] * adv[ni];
                }
#pragma unroll
                for (int off = 8; off >= 1; off >>= 1) {
                    ps += __shfl_xor(ps, off, 16);   // reduce over lr group
                    pd += __shfl_xor(pd, off, 16);
                }
                if (lr == 0) {
                    const int row = m0 + mi * 16 + quad * 4 + r;
                    if (row < Nn) {
                        a_src[row * 4 + wave] = ps;
                        a_dst[row * 4 + wave] = pd;
                    }
                }
            }
    }

    // ---- epilogue 2: H store. C/D: col = lane&15 (lr), row = quad*4 + r ---
    const int n0 = wave * 64;
#pragma unroll
    for (int mi = 0; mi < 4; mi++)
#pragma unroll
        for (int ni = 0; ni < 4; ni++) {
            int col = n0 + ni * 16 + lr;
#pragma unroll
            for (int r = 0; r < 4; r++) {
                int row = m0 + mi * 16 + quad * 4 + r;
                if (row < Nn) H[(size_t)row * 256 + col] = f2bf(acc[mi][ni][r]);
            }
        }
}

// ---------------- CSR build ------------------------------------------------
__global__ void hist_kernel(const int* __restrict__ dst, int* __restrict__ deg,
                            int E, int Nn)
{
    for (int e = blockIdx.x * blockDim.x + threadIdx.x; e < E;
         e += gridDim.x * blockDim.x) {
        int i = dst[e];
        i = ((unsigned)i < (unsigned)Nn) ? i : 0;
        atomicAdd(&deg[i], 1);
    }
}

// One-dispatch exclusive scan with decoupled lookback. 49 blocks x 1024 thr
// (trivially co-resident on 256 CUs): block b posts total | READY to
// bflag[b] (device-scope atomic), lane 0 sums predecessors' flags (spin).
// No cg grid.sync (measured ~110us/sync in R11).
#define SCAN_READY 0x80000000u
__global__ __launch_bounds__(1024) void scan_kernel(
    const int* __restrict__ deg, int* __restrict__ offs, int* __restrict__ cur,
    unsigned* __restrict__ bflag, int Nn)
{
    __shared__ int wsum[16];
    __shared__ int sprefix;
    const int t = threadIdx.x, wv = t >> 6, ln = t & 63;
    const int b = blockIdx.x;
    const int idx = b * 1024 + t;
    int v = (idx < Nn) ? deg[idx] : 0;
    int s = v;
#pragma unroll
    for (int o = 1; o < 64; o <<= 1) {
        int u = __shfl_up(s, o, 64);
        if (ln >= o) s += u;
    }
    if (ln == 63) wsum[wv] = s;
    __syncthreads();
    if (t == 0) {
        int run = 0;
#pragma unroll
        for (int w = 0; w < 16; w++) { int x = wsum[w]; wsum[w] = run; run += x; }
        // post own total (flag value itself carries the data: no fence needed)
        atomicExch(&bflag[b], (unsigned)run | SCAN_READY);
        // lookback: sum all predecessor totals
        unsigned pre = 0;
        for (int pb = b - 1; pb >= 0; pb--) {
            unsigned f;
            do { f = atomicAdd(&bflag[pb], 0u); } while (!(f & SCAN_READY));
            pre += f & ~SCAN_READY;
        }
        sprefix = (int)pre;
    }
    __syncthreads();
    if (idx < Nn) {
        int o = sprefix + wsum[wv] + s - v;          // global exclusive
        offs[idx] = o;
        cur[idx] = o;
    }
}

__global__ void scatter_kernel(
    const int* __restrict__ src, const int* __restrict__ dst,
    int* __restrict__ cur, int* __restrict__ csr_src, int E, int Nn)
{
    for (int e = blockIdx.x * blockDim.x + threadIdx.x; e < E;
         e += gridDim.x * blockDim.x) {
        int j = src[e], i = dst[e];
        j = ((unsigned)j < (unsigned)Nn) ? j : 0;
        i = ((unsigned)i < (unsigned)Nn) ? i : 0;
        int pos = atomicAdd(&cur[i], 1);
        if ((unsigned)pos < (unsigned)E) csr_src[pos] = j;
    }
}

// ---------------- gather: 1 wave/(node, head-pair), 2 ch/thread ------------
// blockIdx = g*8 + s; s&3 picks node sub-group, s>>2 picks head-pair ->
// blocks round-robin XCDs, so XCDs 0-3 serve hp=0 (bytes [0,256) of each H
// row) and XCDs 4-7 serve hp=1. 32-edge phase A: lane sub=lane&31 loads edge
// id + a_src + exp ONCE per 32 edges of its head; ids/weights broadcast via
// __shfl width 32. Rows processed in 16-deep sub-batches; dead tail slots
// clamp to the last valid edge's row (cache-hot, w=0).
__global__ __launch_bounds__(256) void gather_kernel(
    const u16* __restrict__ H, const int* __restrict__ offs,
    const int* __restrict__ deg, const int* __restrict__ csr_src,
    const float* __restrict__ a_src, const float* __restrict__ a_dst,
    const float* __restrict__ bias, const float* __restrict__ prelu,
    float* __restrict__ out, int Nn)
{
    const int wave = threadIdx.x >> 6, lane = threadIdx.x & 63;
    const int g = blockIdx.x >> 3, s = blockIdx.x & 7;
    const int hp = s >> 2;                        // head-pair -> XCD half
    const int node = ((g << 2) + (s & 3)) * 4 + wave;
    if (node >= Nn) return;
    const int hh = lane >> 5;
    const int head = (hp << 1) + hh;
    const int sub = lane & 31;
    const int ch = (head << 6) + sub * 2;         // 2 channels / lane

    const float adv = a_dst[node * 4 + head];
    const float ws = wexp(a_src[node * 4 + head] + adv);
    float acc0, acc1, sumw = 0.f;                 // sumw: own edges only
    {   // self loop
        const uint32_t hv = *(const uint32_t*)(H + (size_t)node * 256 + ch);
        acc0 = ws * bf2f((u16)hv);
        acc1 = ws * bf2f((u16)(hv >> 16));
    }
    const int d = deg[node];
    const int* __restrict__ cp = csr_src + offs[node];

    for (int k = 0; k < d; k += 32) {
        const int q = d - k;                      // edges left (>=1)
        const int es = (sub < q) ? sub : q - 1;
        const int jj = cp[k + es];                // in-range always
        float ww = wexp(a_src[jj * 4 + head] + adv);
        ww = (sub < q) ? ww : 0.f;
        sumw += ww;
        const int nh = (q > 16) ? 2 : 1;
        for (int half = 0; half < nh; half++) {
            const int hb = half << 4;
            uint32_t hv[16];
#pragma unroll
            for (int t = 0; t < 16; t++) {
                const int jt = __shfl(jj, hb + t, 32);
                hv[t] = *(const uint32_t*)(H + ((size_t)jt << 8) + ch);
            }
#pragma unroll
            for (int t = 0; t < 16; t++) {
                const float w = __shfl(ww, hb + t, 32);
                acc0 += w * bf2f((u16)hv[t]);
                acc1 += w * bf2f((u16)(hv[t] >> 16));
            }
        }
    }
    // total edge weight: reduce per-lane partials over the 32-lane head group
#pragma unroll
    for (int off = 16; off >= 1; off >>= 1)
        sumw += __shfl_xor(sumw, off, 32);

    const float inv = 1.f / (ws + sumw + 1e-16f);
    const float pa = prelu[0];
    float o0 = acc0 * inv + bias[ch];
    float o1 = acc1 * inv + bias[ch + 1];
    o0 = o0 >= 0.f ? o0 : pa * o0;
    o1 = o1 >= 0.f ? o1 : pa * o1;
    float2 ov; ov.x = o0; ov.y = o1;
    *(float2*)(out + (size_t)node * 256 + ch) = ov;
}

// ---------------------------------------------------------------------------
extern "C" void kernel_launch(void* const* d_in, const int* in_sizes, int n_in,
                              void* d_out, int out_size, void* d_ws, size_t ws_size,
                              hipStream_t stream)
{
    const float* X    = (const float*)d_in[0];
    const int*   EI   = (const int*)d_in[1];
    const float* W    = (const float*)d_in[2];
    const float* attS = (const float*)d_in[3];
    const float* attD = (const float*)d_in[4];
    const float* bias = (const float*)d_in[5];
    const float* pa   = (const float*)d_in[6];

    const int Nn = in_sizes[0] / 256;   // 50000
    const int E  = in_sizes[1] / 2;     // 800000
    const int* esrc = EI;
    const int* edst = EI + E;
    const int nscan = (Nn + 1023) / 1024;   // 49

    // workspace carve (~31 MB), all segments 16B-aligned
    char* p = (char*)d_ws;
    u16*     H       = (u16*)p;      p += (size_t)Nn * 256 * 2;
    float*   a_src   = (float*)p;    p += (size_t)Nn * 4 * 4;
    float*   a_dst   = (float*)p;    p += (size_t)Nn * 4 * 4;
    u16*     Wfh     = (u16*)p;      p += 256 * 256 * 2;
    u16*     Wfl     = (u16*)p;      p += 256 * 256 * 2;
    int*     deg     = (int*)p;      p += (size_t)Nn * 4;
    int*     offs    = (int*)p;      p += (size_t)Nn * 4;
    int*     cur     = (int*)p;      p += (size_t)Nn * 4;
    unsigned* bflag  = (unsigned*)p; p += 256 * 4;
    int*     csr_src = (int*)p;      p += ((size_t)E + 16) * 4;

    prep_kernel<<<256, 256, 0, stream>>>(W, Wfh, Wfl, deg, bflag, Nn, nscan);
    gemm_kernel<<<(Nn + 63) / 64, 256, 0, stream>>>(X, Wfh, Wfl, attS, attD,
                                                    H, a_src, a_dst, Nn);
    hist_kernel<<<2048, 256, 0, stream>>>(edst, deg, E, Nn);
    scan_kernel<<<nscan, 1024, 0, stream>>>(deg, offs, cur, bflag, Nn);
    scatter_kernel<<<2048, 256, 0, stream>>>(esrc, edst, cur, csr_src, E, Nn);
    const int gblocks = ((Nn + 15) / 16) * 8;
    gather_kernel<<<gblocks, 256, 0, stream>>>(H, offs, deg, csr_src,
                                               a_src, a_dst, bias, pa,
                                               (float*)d_out, Nn);
}

// Round 5
// 240.159 us; speedup vs baseline: 3.2248x; 1.2452x over previous
//
#include <hip/hip_runtime.h>
#include <stdint.h>

// GAT forward, MI355X. FP32 in/out; edge_index int32. N=50000, E=800000,
// HEADS=4, C=64 (HC=256).
// Pipeline (R13):
//   prep: trans (W -> frag-major split bf16) + zero scan flags.
//   gemm: H = x@W via split-bf16 MFMA (3 terms, err ~2^-17), H stored bf16.
//         att logits a_src/a_dst fused in epilogue (wave=head).
//   CSR build — ZERO global atomics (R12 audit: hist+scatter ~140us total,
//   dominated by 1.6M device-scope random atomics executing at the shared
//   coherence point behind 8 non-coherent L2s). 2-pass radix partition:
//     p1h:  256 blocks x chunk of E/256 edges; LDS hist over coarse bucket
//           (dst>>8, nb1=196); dump cnt1[bucket*256+blk] (bucket-major).
//     scan: decoupled-lookback exclusive scan of cnt1 (len 50176; proven
//           R12 structure, 49 co-resident blocks, no cg grid.sync).
//     p1s:  re-read chunk; LDS cursors cur1[b]=base1[b*256+blk]; scatter
//           packed rec = src | (dst&255)<<16 (both fit: N<65536) to part[].
//     p2:   1 block per bucket: LDS fine hist (dst&255) + 256-scan ->
//           deg/offs written directly; LDS cursors place csr_src.
//   gather: out = (w_self*h_i + sum_j w_j*h_j)/(sum w) + bias, PReLU.
//         One wave per (node, head-pair); 2 ch/lane; 32-edge phase A (1 cp
//         load + 1 a_src load + 1 exp per lane per 32 edges of its head);
//         ids/weights broadcast via __shfl width 32; 16-deep row sub-
//         batches. Head-pair steered to XCD half via blockIdx&7: per-XCD H
//         footprint halves (FETCH 211->189MB measured R12).
// Softmax shift omitted: logits fp32-exact-ish (err ~1e-4), |e|<~12 ->
// exp<=1.6e5, fp32-safe; softmax is shift-invariant. Dominant output error =
// bf16 H storage (~0.016 absmax vs 0.0575 threshold, verified rounds 3-12).

using u16 = unsigned short;
typedef float f32x4 __attribute__((ext_vector_type(4)));
typedef __bf16 bf16x8 __attribute__((ext_vector_type(8)));
typedef u16 u16x8 __attribute__((ext_vector_type(8)));

#define NEG 0.2f
#define APAD 264   // 256 + 8 u16 pad: row stride 528 B -> 2-way LDS aliasing (free)
#define NBLK1 256  // pass-1 partition blocks (= chunk count)

__device__ __forceinline__ float bf2f(u16 u) {
    union { uint32_t i; float f; } v; v.i = ((uint32_t)u) << 16; return v.f;
}
__device__ __forceinline__ u16 f2bf(float f) {          // RNE
    union { float f; uint32_t i; } v; v.f = f;
    uint32_t r = v.i + 0x7FFFu + ((v.i >> 16) & 1u);
    return (u16)(r >> 16);
}
// trunc split: f ~= hi + lo with |err| ~ 2^-17 |f|
__device__ __forceinline__ void split2(float f, u16& h, u16& l) {
    union { float f; uint32_t i; } v; v.f = f;
    h = (u16)(v.i >> 16);
    float r = f - bf2f(h);
    union { float f; uint32_t i; } w; w.f = r;
    l = (u16)(w.i >> 16);
}
__device__ __forceinline__ float wexp(float e) {
    e = e >= 0.f ? e : NEG * e;
    return __expf(e);
}

// ---------------- prep: trans (W -> frag-major split bf16) + zero flags ----
__global__ __launch_bounds__(256) void prep_kernel(
    const float* __restrict__ W, u16* __restrict__ Wfh, u16* __restrict__ Wfl,
    unsigned* __restrict__ bflag, int nscan)
{
    const int tid = threadIdx.x;
    const int gt = blockIdx.x * 256 + tid;
    if (gt < nscan) bflag[gt] = 0u;
    // Wf[((kg*16+nb)*64+l)*8+j] =
    //   split(W[(kg*32+(l>>4)*8+j)*256 + nb*16+(l&15)])
    const int f = blockIdx.x * 4 + (tid >> 6);
    const int l = tid & 63;
    const int kg = f >> 4, nb = f & 15;
    const int n = nb * 16 + (l & 15);
    const int kb = kg * 32 + (l >> 4) * 8;
    u16x8 hv, lv;
#pragma unroll
    for (int j = 0; j < 8; j++) {
        u16 th, tl;
        split2(W[(size_t)(kb + j) * 256 + n], th, tl);
        hv[j] = th;
        lv[j] = tl;
    }
    *(u16x8*)(Wfh + ((size_t)f * 64 + l) * 8) = hv;
    *(u16x8*)(Wfl + ((size_t)f * 64 + l) * 8) = lv;
}

// ---------------- GEMM: H = x @ W, LDS-staged A, frag-major B --------------
// att logits fused into the epilogue (wave w owns head w's columns).
__global__ __launch_bounds__(256, 2) void gemm_kernel(
    const float* __restrict__ X, const u16* __restrict__ Wfh,
    const u16* __restrict__ Wfl, const float* __restrict__ attS,
    const float* __restrict__ attD, u16* __restrict__ H,
    float* __restrict__ a_src, float* __restrict__ a_dst, int Nn)
{
    __shared__ u16 Ah[64 * APAD];
    __shared__ u16 Al[64 * APAD];
    const int tid = threadIdx.x, m0 = blockIdx.x * 64;
    const int wave = tid >> 6, lane = tid & 63;
    const int quad = lane >> 4, lr = lane & 15;

    // ---- stage X tile (64 rows x 256 cols) as split bf16 ----
#pragma unroll
    for (int i = 0; i < 16; i++) {
        const int f = i * 256 + tid;            // float4 index in tile
        const int row = f >> 6;                 // 64 float4 per row
        const int c4 = (f & 63) * 4;
        int grow = m0 + row;
        if (grow >= Nn) grow = Nn - 1;          // clamp; stores guarded
        const float4 v = *(const float4*)(X + (size_t)grow * 256 + c4);
        u16 h0, l0, h1, l1, h2, l2, h3, l3;
        split2(v.x, h0, l0); split2(v.y, h1, l1);
        split2(v.z, h2, l2); split2(v.w, h3, l3);
        uint2 hp, lp;
        hp.x = (uint32_t)h0 | ((uint32_t)h1 << 16);
        hp.y = (uint32_t)h2 | ((uint32_t)h3 << 16);
        lp.x = (uint32_t)l0 | ((uint32_t)l1 << 16);
        lp.y = (uint32_t)l2 | ((uint32_t)l3 << 16);
        *(uint2*)(Ah + row * APAD + c4) = hp;   // 8B aligned
        *(uint2*)(Al + row * APAD + c4) = lp;
    }
    __syncthreads();

    f32x4 acc[4][4] = {};                       // [mi][ni]
    bf16x8 bh[2][4], bl[2][4];                  // B double buffer

    // prologue: kg=0 B frags (frag id = kg*16 + wave*4 + ni)
#pragma unroll
    for (int ni = 0; ni < 4; ni++) {
        const size_t o = ((size_t)(wave * 4 + ni) * 64 + lane) * 8;
        bh[0][ni] = *(const bf16x8*)(Wfh + o);
        bl[0][ni] = *(const bf16x8*)(Wfl + o);
    }

#pragma unroll
    for (int kg = 0; kg < 8; kg++) {
        const int st = kg & 1, ns = st ^ 1;
        if (kg < 7) {                           // prefetch kg+1 B
#pragma unroll
            for (int ni = 0; ni < 4; ni++) {
                const size_t o = ((size_t)((kg + 1) * 16 + wave * 4 + ni) * 64 + lane) * 8;
                bh[ns][ni] = *(const bf16x8*)(Wfh + o);
                bl[ns][ni] = *(const bf16x8*)(Wfl + o);
            }
        }
        bf16x8 ah[4], al[4];
#pragma unroll
        for (int mi = 0; mi < 4; mi++) {
            const int o = (mi * 16 + lr) * APAD + kg * 32 + quad * 8;
            ah[mi] = *(const bf16x8*)(Ah + o);  // ds_read_b128
            al[mi] = *(const bf16x8*)(Al + o);
        }
#pragma unroll
        for (int ni = 0; ni < 4; ni++)
#pragma unroll
            for (int mi = 0; mi < 4; mi++) {
                acc[mi][ni] = __builtin_amdgcn_mfma_f32_16x16x32_bf16(
                    ah[mi], bh[st][ni], acc[mi][ni], 0, 0, 0);
                acc[mi][ni] = __builtin_amdgcn_mfma_f32_16x16x32_bf16(
                    ah[mi], bl[st][ni], acc[mi][ni], 0, 0, 0);
                acc[mi][ni] = __builtin_amdgcn_mfma_f32_16x16x32_bf16(
                    al[mi], bh[st][ni], acc[mi][ni], 0, 0, 0);
            }
    }

    // ---- epilogue 1: att logits from fp32 acc (wave = head) ----
    // a_src[row][wave] = sum_c acc(row, c) * attS[wave][c]; c = ni*16+lr.
    {
        float asv[4], adv[4];
#pragma unroll
        for (int ni = 0; ni < 4; ni++) {
            asv[ni] = attS[wave * 64 + ni * 16 + lr];
            adv[ni] = attD[wave * 64 + ni * 16 + lr];
        }
#pragma unroll
        for (int mi = 0; mi < 4; mi++)
#pragma unroll
            for (int r = 0; r < 4; r++) {
                float ps = 0.f, pd = 0.f;
#pragma unroll
                for (int ni = 0; ni < 4; ni++) {
                    ps += acc[mi][ni][r] * asv[ni];
                    pd += acc[mi][ni][r] * adv[ni];
                }
#pragma unroll
                for (int off = 8; off >= 1; off >>= 1) {
                    ps += __shfl_xor(ps, off, 16);   // reduce over lr group
                    pd += __shfl_xor(pd, off, 16);
                }
                if (lr == 0) {
                    const int row = m0 + mi * 16 + quad * 4 + r;
                    if (row < Nn) {
                        a_src[row * 4 + wave] = ps;
                        a_dst[row * 4 + wave] = pd;
                    }
                }
            }
    }

    // ---- epilogue 2: H store. C/D: col = lane&15 (lr), row = quad*4 + r ---
    const int n0 = wave * 64;
#pragma unroll
    for (int mi = 0; mi < 4; mi++)
#pragma unroll
        for (int ni = 0; ni < 4; ni++) {
            int col = n0 + ni * 16 + lr;
#pragma unroll
            for (int r = 0; r < 4; r++) {
                int row = m0 + mi * 16 + quad * 4 + r;
                if (row < Nn) H[(size_t)row * 256 + col] = f2bf(acc[mi][ni][r]);
            }
        }
}

// ---------------- CSR build: 2-pass radix partition, LDS atomics only ------
// p1h: per-chunk LDS hist over coarse bucket (dst>>8), bucket-major dump.
__global__ __launch_bounds__(256) void p1hist_kernel(
    const int* __restrict__ edst, int* __restrict__ cnt1,
    int E, int Nn, int nb1, int chunk)
{
    __shared__ int h1[256];
    const int tid = threadIdx.x;
    h1[tid] = 0;
    __syncthreads();
    const int e0 = blockIdx.x * chunk;
    const int e1 = (e0 + chunk < E) ? e0 + chunk : E;
    for (int e = e0 + tid; e < e1; e += 256) {
        int i = edst[e];
        i = ((unsigned)i < (unsigned)Nn) ? i : 0;
        atomicAdd(&h1[i >> 8], 1);               // LDS atomic
    }
    __syncthreads();
    if (tid < nb1) cnt1[tid * NBLK1 + blockIdx.x] = h1[tid];
}

// One-dispatch exclusive scan with decoupled lookback (proven R12). 49
// co-resident blocks; block b posts total|READY, lane 0 sums predecessors.
#define SCAN_READY 0x80000000u
__global__ __launch_bounds__(1024) void scan_kernel(
    const int* __restrict__ in, int* __restrict__ out,
    unsigned* __restrict__ bflag, int len)
{
    __shared__ int wsum[16];
    __shared__ int sprefix;
    const int t = threadIdx.x, wv = t >> 6, ln = t & 63;
    const int b = blockIdx.x;
    const int idx = b * 1024 + t;
    int v = (idx < len) ? in[idx] : 0;
    int s = v;
#pragma unroll
    for (int o = 1; o < 64; o <<= 1) {
        int u = __shfl_up(s, o, 64);
        if (ln >= o) s += u;
    }
    if (ln == 63) wsum[wv] = s;
    __syncthreads();
    if (t == 0) {
        int run = 0;
#pragma unroll
        for (int w = 0; w < 16; w++) { int x = wsum[w]; wsum[w] = run; run += x; }
        atomicExch(&bflag[b], (unsigned)run | SCAN_READY);
        unsigned pre = 0;
        for (int pb = b - 1; pb >= 0; pb--) {
            unsigned f;
            do { f = atomicAdd(&bflag[pb], 0u); } while (!(f & SCAN_READY));
            pre += f & ~SCAN_READY;
        }
        sprefix = (int)pre;
    }
    __syncthreads();
    if (idx < len) out[idx] = sprefix + wsum[wv] + s - v;
}

// p1s: scatter packed records (src | fine<<16) into bucket partitions.
// LDS cursors seeded from base1 -> exact positions, no global atomics.
__global__ __launch_bounds__(256) void p1scat_kernel(
    const int* __restrict__ esrc, const int* __restrict__ edst,
    const int* __restrict__ base1, uint32_t* __restrict__ part,
    int E, int Nn, int nb1, int chunk)
{
    __shared__ int cur1[256];
    const int tid = threadIdx.x;
    if (tid < nb1) cur1[tid] = base1[tid * NBLK1 + blockIdx.x];
    __syncthreads();
    const int e0 = blockIdx.x * chunk;
    const int e1 = (e0 + chunk < E) ? e0 + chunk : E;
    for (int e = e0 + tid; e < e1; e += 256) {
        int i = edst[e];
        i = ((unsigned)i < (unsigned)Nn) ? i : 0;
        int j = esrc[e];
        j = ((unsigned)j < (unsigned)Nn) ? j : 0;
        const int pos = atomicAdd(&cur1[i >> 8], 1);   // LDS atomic
        part[pos] = (uint32_t)j | ((uint32_t)(i & 255) << 16);  // N<65536
    }
}

// p2: one block per coarse bucket. Fine hist (dst&255) + 256-wide scan ->
// deg/offs emitted directly; LDS cursors place csr_src at final positions.
__global__ __launch_bounds__(256) void p2_kernel(
    const uint32_t* __restrict__ part, const int* __restrict__ base1,
    int* __restrict__ deg, int* __restrict__ offs, int* __restrict__ csr_src,
    int E, int Nn, int nb1)
{
    __shared__ int h2[256];
    __shared__ int wsum[4];
    const int b = blockIdx.x, tid = threadIdx.x;
    const int ln = tid & 63, wv = tid >> 6;
    const int bstart = base1[b * NBLK1];
    const int bend = (b == nb1 - 1) ? E : base1[(b + 1) * NBLK1];
    h2[tid] = 0;
    __syncthreads();
    for (int e = bstart + tid; e < bend; e += 256)
        atomicAdd(&h2[part[e] >> 16], 1);             // LDS atomic
    __syncthreads();
    const int cnt = h2[tid];
    int s = cnt;
#pragma unroll
    for (int o = 1; o < 64; o <<= 1) {
        int u = __shfl_up(s, o, 64);
        if (ln >= o) s += u;
    }
    if (ln == 63) wsum[wv] = s;
    __syncthreads();
    int wpre = 0;
#pragma unroll
    for (int w2 = 0; w2 < 4; w2++) wpre += (w2 < wv) ? wsum[w2] : 0;
    const int ex = bstart + wpre + s - cnt;            // global exclusive
    const int node = (b << 8) + tid;
    if (node < Nn) { deg[node] = cnt; offs[node] = ex; }
    __syncthreads();
    h2[tid] = ex;                                      // reuse as cursors
    __syncthreads();
    for (int e = bstart + tid; e < bend; e += 256) {
        const uint32_t p = part[e];
        const int pos = atomicAdd(&h2[p >> 16], 1);    // LDS atomic
        csr_src[pos] = (int)(p & 0xFFFFu);
    }
}

// ---------------- gather: 1 wave/(node, head-pair), 2 ch/thread ------------
// blockIdx = g*8 + s; s&3 picks node sub-group, s>>2 picks head-pair ->
// blocks round-robin XCDs, so XCDs 0-3 serve hp=0 (bytes [0,256) of each H
// row) and XCDs 4-7 serve hp=1. 32-edge phase A: lane sub=lane&31 loads edge
// id + a_src + exp ONCE per 32 edges of its head; ids/weights broadcast via
// __shfl width 32. Rows processed in 16-deep sub-batches; dead tail slots
// clamp to the last valid edge's row (cache-hot, w=0).
__global__ __launch_bounds__(256) void gather_kernel(
    const u16* __restrict__ H, const int* __restrict__ offs,
    const int* __restrict__ deg, const int* __restrict__ csr_src,
    const float* __restrict__ a_src, const float* __restrict__ a_dst,
    const float* __restrict__ bias, const float* __restrict__ prelu,
    float* __restrict__ out, int Nn)
{
    const int wave = threadIdx.x >> 6, lane = threadIdx.x & 63;
    const int g = blockIdx.x >> 3, s = blockIdx.x & 7;
    const int hp = s >> 2;                        // head-pair -> XCD half
    const int node = ((g << 2) + (s & 3)) * 4 + wave;
    if (node >= Nn) return;
    const int hh = lane >> 5;
    const int head = (hp << 1) + hh;
    const int sub = lane & 31;
    const int ch = (head << 6) + sub * 2;         // 2 channels / lane

    const float adv = a_dst[node * 4 + head];
    const float ws = wexp(a_src[node * 4 + head] + adv);
    float acc0, acc1, sumw = 0.f;                 // sumw: own edges only
    {   // self loop
        const uint32_t hv = *(const uint32_t*)(H + (size_t)node * 256 + ch);
        acc0 = ws * bf2f((u16)hv);
        acc1 = ws * bf2f((u16)(hv >> 16));
    }
    const int d = deg[node];
    const int* __restrict__ cp = csr_src + offs[node];

    for (int k = 0; k < d; k += 32) {
        const int q = d - k;                      // edges left (>=1)
        const int es = (sub < q) ? sub : q - 1;
        const int jj = cp[k + es];                // in-range always
        float ww = wexp(a_src[jj * 4 + head] + adv);
        ww = (sub < q) ? ww : 0.f;
        sumw += ww;
        const int nh = (q > 16) ? 2 : 1;
        for (int half = 0; half < nh; half++) {
            const int hb = half << 4;
            uint32_t hv[16];
#pragma unroll
            for (int t = 0; t < 16; t++) {
                const int jt = __shfl(jj, hb + t, 32);
                hv[t] = *(const uint32_t*)(H + ((size_t)jt << 8) + ch);
            }
#pragma unroll
            for (int t = 0; t < 16; t++) {
                const float w = __shfl(ww, hb + t, 32);
                acc0 += w * bf2f((u16)hv[t]);
                acc1 += w * bf2f((u16)(hv[t] >> 16));
            }
        }
    }
    // total edge weight: reduce per-lane partials over the 32-lane head group
#pragma unroll
    for (int off = 16; off >= 1; off >>= 1)
        sumw += __shfl_xor(sumw, off, 32);

    const float inv = 1.f / (ws + sumw + 1e-16f);
    const float pa = prelu[0];
    float o0 = acc0 * inv + bias[ch];
    float o1 = acc1 * inv + bias[ch + 1];
    o0 = o0 >= 0.f ? o0 : pa * o0;
    o1 = o1 >= 0.f ? o1 : pa * o1;
    float2 ov; ov.x = o0; ov.y = o1;
    *(float2*)(out + (size_t)node * 256 + ch) = ov;
}

// ---------------------------------------------------------------------------
extern "C" void kernel_launch(void* const* d_in, const int* in_sizes, int n_in,
                              void* d_out, int out_size, void* d_ws, size_t ws_size,
                              hipStream_t stream)
{
    const float* X    = (const float*)d_in[0];
    const int*   EI   = (const int*)d_in[1];
    const float* W    = (const float*)d_in[2];
    const float* attS = (const float*)d_in[3];
    const float* attD = (const float*)d_in[4];
    const float* bias = (const float*)d_in[5];
    const float* pa   = (const float*)d_in[6];

    const int Nn = in_sizes[0] / 256;   // 50000
    const int E  = in_sizes[1] / 2;     // 800000
    const int* esrc = EI;
    const int* edst = EI + E;

    const int nb1   = (Nn + 255) >> 8;              // 196 coarse buckets
    const int slen  = nb1 * NBLK1;                  // 50176
    const int nscan = (slen + 1023) / 1024;         // 49 (co-resident)
    const int chunk = (E + NBLK1 - 1) / NBLK1;      // 3125

    // workspace carve (~35 MB), all segments 16B-aligned
    char* p = (char*)d_ws;
    u16*      H       = (u16*)p;      p += (size_t)Nn * 256 * 2;
    float*    a_src   = (float*)p;    p += (size_t)Nn * 4 * 4;
    float*    a_dst   = (float*)p;    p += (size_t)Nn * 4 * 4;
    u16*      Wfh     = (u16*)p;      p += 256 * 256 * 2;
    u16*      Wfl     = (u16*)p;      p += 256 * 256 * 2;
    int*      deg     = (int*)p;      p += (size_t)Nn * 4;
    int*      offs    = (int*)p;      p += (size_t)Nn * 4;
    int*      cnt1    = (int*)p;      p += (size_t)256 * NBLK1 * 4;
    int*      base1   = (int*)p;      p += (size_t)256 * NBLK1 * 4;
    unsigned* bflag   = (unsigned*)p; p += 256 * 4;
    uint32_t* part    = (uint32_t*)p; p += (size_t)E * 4;
    int*      csr_src = (int*)p;      p += ((size_t)E + 16) * 4;

    prep_kernel<<<32, 256, 0, stream>>>(W, Wfh, Wfl, bflag, nscan);
    gemm_kernel<<<(Nn + 63) / 64, 256, 0, stream>>>(X, Wfh, Wfl, attS, attD,
                                                    H, a_src, a_dst, Nn);
    p1hist_kernel<<<NBLK1, 256, 0, stream>>>(edst, cnt1, E, Nn, nb1, chunk);
    scan_kernel<<<nscan, 1024, 0, stream>>>(cnt1, base1, bflag, slen);
    p1scat_kernel<<<NBLK1, 256, 0, stream>>>(esrc, edst, base1, part,
                                             E, Nn, nb1, chunk);
    p2_kernel<<<nb1, 256, 0, stream>>>(part, base1, deg, offs, csr_src,
                                       E, Nn, nb1);
    const int gblocks = ((Nn + 15) / 16) * 8;
    gather_kernel<<<gblocks, 256, 0, stream>>>(H, offs, deg, csr_src,
                                               a_src, a_dst, bias, pa,
                                               (float*)d_out, Nn);
}